// Round 1
// baseline (9367.587 us; speedup 1.0000x reference)
//
#include <hip/hip_runtime.h>
#include <cstdint>
#include <cstddef>

// ---------------------------------------------------------------------------
// MinkTrunk forward: sparse convs (ELL gather form) + training-mode BN + ReLU.
// Round 0: correctness-first f32 VALU implementation.
// ---------------------------------------------------------------------------

__global__ void build_ell_kernel(const int* __restrict__ in_idx,
                                 const int* __restrict__ out_idx,
                                 int K, int P, int n_in, int n_out,
                                 int* __restrict__ ell) {
  int i = blockIdx.x * 256 + threadIdx.x;
  if (i >= K * P) return;
  int vin = in_idx[i];
  int vout = out_idx[i];
  if (vin < n_in && vout < n_out) {
    ell[(size_t)vout * K + (i / P)] = vin;   // slot unique per (out,k)
  }
}

// One thread per (output row, output channel). ell==nullptr -> dense (in=row).
template <int CIN, int COUT>
__global__ void gather_conv_kernel(const float* __restrict__ x,
                                   const float* __restrict__ W,
                                   const int* __restrict__ ell,
                                   int K, int n_out,
                                   float* __restrict__ out) {
  constexpr int ROWS = 256 / COUT;
  const int c = threadIdx.x % COUT;
  const int r = threadIdx.x / COUT;
  const long row = (long)blockIdx.x * ROWS + r;
  if (row >= n_out) return;
  float acc = 0.f;
  for (int k = 0; k < K; ++k) {
    const int in = ell ? ell[row * (long)K + k] : (int)row;
    if (in < 0) continue;
    const float* __restrict__ xr = x + (long)in * CIN;
    const float* __restrict__ wk = W + (size_t)k * CIN * COUT + c;
#pragma unroll 8
    for (int ci = 0; ci < CIN; ++ci)
      acc = fmaf(xr[ci], wk[(size_t)ci * COUT], acc);
  }
  out[row * (long)COUT + c] = acc;
}

// BN pass 1: per-block partial sum/sumsq per channel (deterministic layout).
template <int C>
__global__ void bn_reduce1_kernel(const float* __restrict__ x, int n,
                                  float* __restrict__ part) {
  constexpr int RL = 256 / C;
  const int c = threadIdx.x % C;
  const int rl = threadIdx.x / C;
  float s = 0.f, ss = 0.f;
  for (long row = (long)blockIdx.x * RL + rl; row < n;
       row += (long)gridDim.x * RL) {
    float v = x[row * C + c];
    s += v;
    ss += v * v;
  }
  __shared__ float sh[512];
  sh[threadIdx.x] = s;
  sh[256 + threadIdx.x] = ss;
  __syncthreads();
  if (rl == 0) {
#pragma unroll
    for (int j = 1; j < RL; ++j) {
      s += sh[j * C + c];
      ss += sh[256 + j * C + c];
    }
    part[(size_t)blockIdx.x * 2 * C + c] = s;
    part[(size_t)blockIdx.x * 2 * C + C + c] = ss;
  }
}

// BN pass 2: fixed-order reduction of G partials -> stats[0..C)=sum, [C..2C)=sumsq
template <int C>
__global__ void bn_reduce2_kernel(const float* __restrict__ part, int G,
                                  float* __restrict__ stats) {
  const int c = threadIdx.x;
  float s = 0.f, ss = 0.f;
  for (int g = 0; g < G; ++g) {
    s += part[(size_t)g * 2 * C + c];
    ss += part[(size_t)g * 2 * C + C + c];
  }
  stats[c] = s;
  stats[C + c] = ss;
}

// BN apply (optionally + residual, optionally ReLU), elementwise.
template <int C, bool RELU, bool RES>
__global__ void bn_apply_kernel(const float* __restrict__ x,
                                const float* __restrict__ stats,
                                const float* __restrict__ gamma,
                                const float* __restrict__ beta,
                                const float* __restrict__ res,
                                long total, float inv_n,
                                float* __restrict__ out) {
  long i = (long)blockIdx.x * 256 + threadIdx.x;
  if (i >= total) return;
  const int c = (int)(i % C);
  const float m = stats[c] * inv_n;
  const float var = stats[C + c] * inv_n - m * m;
  const float sc = rsqrtf(var + 1e-5f) * gamma[c];
  float v = (x[i] - m) * sc + beta[c];
  if (RES) v += res[i];
  if (RELU) v = fmaxf(v, 0.f);
  out[i] = v;
}

// ---------------------------------------------------------------------------

extern "C" void kernel_launch(void* const* d_in, const int* in_sizes, int n_in,
                              void* d_out, int out_size, void* d_ws,
                              size_t ws_size, hipStream_t stream) {
  const float* feats = (const float*)d_in[0];
  const float* W0  = (const float*)d_in[1];
  const float* g0  = (const float*)d_in[2];
  const float* b0  = (const float*)d_in[3];
  const float* Ws1 = (const float*)d_in[4];
  const float* gs1 = (const float*)d_in[5];
  const float* bs1 = (const float*)d_in[6];
  const float* Wa1 = (const float*)d_in[7];
  const float* ga1 = (const float*)d_in[8];
  const float* ba1 = (const float*)d_in[9];
  const float* Wb1 = (const float*)d_in[10];
  const float* gb1 = (const float*)d_in[11];
  const float* bb1 = (const float*)d_in[12];
  const float* Ws2 = (const float*)d_in[13];
  const float* gs2 = (const float*)d_in[14];
  const float* bs2 = (const float*)d_in[15];
  const float* Wa2 = (const float*)d_in[16];
  const float* ga2 = (const float*)d_in[17];
  const float* ba2 = (const float*)d_in[18];
  const float* Wb2 = (const float*)d_in[19];
  const float* gb2 = (const float*)d_in[20];
  const float* bb2 = (const float*)d_in[21];
  const float* Wd2 = (const float*)d_in[22];
  const float* gd2 = (const float*)d_in[23];
  const float* bd2 = (const float*)d_in[24];
  const float* Ws3 = (const float*)d_in[25];
  const float* gs3 = (const float*)d_in[26];
  const float* bs3 = (const float*)d_in[27];
  const float* Wa3 = (const float*)d_in[28];
  const float* ga3 = (const float*)d_in[29];
  const float* ba3 = (const float*)d_in[30];
  const float* Wb3 = (const float*)d_in[31];
  const float* gb3 = (const float*)d_in[32];
  const float* bb3 = (const float*)d_in[33];
  const float* Wd3 = (const float*)d_in[34];
  const float* gd3 = (const float*)d_in[35];
  const float* bd3 = (const float*)d_in[36];
  const int* im0  = (const int*)d_in[40];
  const int* om0  = (const int*)d_in[41];
  const int* ims1 = (const int*)d_in[42];
  const int* oms1 = (const int*)d_in[43];
  const int* imb1 = (const int*)d_in[44];
  const int* omb1 = (const int*)d_in[45];
  const int* ims2 = (const int*)d_in[46];
  const int* oms2 = (const int*)d_in[47];
  const int* imb2 = (const int*)d_in[48];
  const int* omb2 = (const int*)d_in[49];
  const int* ims3 = (const int*)d_in[50];
  const int* oms3 = (const int*)d_in[51];
  const int* imb3 = (const int*)d_in[52];
  const int* omb3 = (const int*)d_in[53];

  const int n0 = in_sizes[0];
  const int n1 = in_sizes[37] / 3;
  const int n2 = in_sizes[38] / 3;
  const int n3 = in_sizes[39] / 3;
  const int P0  = in_sizes[40] / 125;
  const int Ps1 = in_sizes[42] / 8;
  const int Pb1 = in_sizes[44] / 27;
  const int Ps2 = in_sizes[46] / 8;
  const int Pb2 = in_sizes[48] / 27;
  const int Ps3 = in_sizes[50] / 8;
  const int Pb3 = in_sizes[52] / 27;

  // ---- workspace carve (peak ~137 MB) ----
  auto maxsz = [](size_t a, size_t b) { return a > b ? a : b; };
  char* w = (char*)d_ws;
  auto carve = [&](size_t bytes) {
    char* p = w;
    w += (bytes + 255) & ~(size_t)255;
    return p;
  };
  size_t ellElems = maxsz((size_t)n0 * 125,
                          maxsz((size_t)n1 * 27, (size_t)n2 * 27));
  int* ell = (int*)carve(ellElems * sizeof(int));
  float* part = (float*)carve((size_t)256 * 2 * 256 * sizeof(float));
  float* stats = (float*)carve((size_t)2 * 256 * sizeof(float));
  size_t cap1 = maxsz((size_t)n0 * 64,
                      maxsz((size_t)n2 * 128, (size_t)n3 * 128));
  size_t cap2 = maxsz((size_t)n1 * 64,
                      maxsz((size_t)n2 * 128, (size_t)n3 * 256));
  float* buf1 = (float*)carve(cap1 * sizeof(float));
  float* buf2 = (float*)carve(cap2 * sizeof(float));
  float* buf3 = (float*)carve(cap2 * sizeof(float));
  float* buf4 = (float*)carve(cap2 * sizeof(float));
  (void)ws_size;

  // ---- helpers ----
  auto conv = [&](const float* x, const float* W, const int* im, const int* om,
                  int K, int P, int nin, int nout, int cin, int cout,
                  float* out) {
    hipMemsetAsync(ell, 0xFF, (size_t)nout * K * sizeof(int), stream);
    int tot = K * P;
    build_ell_kernel<<<(tot + 255) / 256, 256, 0, stream>>>(im, om, K, P, nin,
                                                            nout, ell);
#define CONV_CASE(CI, CO)                                                      \
  else if (cin == CI && cout == CO) {                                          \
    int grid = (nout + (256 / CO) - 1) / (256 / CO);                           \
    gather_conv_kernel<CI, CO><<<grid, 256, 0, stream>>>(x, W, ell, K, nout,   \
                                                         out);                 \
  }
    if (false) {}
    CONV_CASE(1, 64)
    CONV_CASE(64, 64)
    CONV_CASE(64, 128)
    CONV_CASE(128, 128)
    CONV_CASE(128, 256)
    CONV_CASE(256, 256)
#undef CONV_CASE
  };

  auto dense = [&](const float* x, const float* W, int n, int cin, int cout,
                   float* out) {
#define DENSE_CASE(CI, CO)                                                     \
  else if (cin == CI && cout == CO) {                                          \
    int grid = (n + (256 / CO) - 1) / (256 / CO);                              \
    gather_conv_kernel<CI, CO><<<grid, 256, 0, stream>>>(x, W, nullptr, 1, n,  \
                                                         out);                 \
  }
    if (false) {}
    DENSE_CASE(64, 128)
    DENSE_CASE(128, 256)
#undef DENSE_CASE
  };

  auto bn = [&](const float* x, int n, int C, const float* gamma,
                const float* beta, const float* res, bool relu, float* out) {
    const int G = 256;
    float invn = 1.0f / (float)n;
    long total = (long)n * C;
    int agrid = (int)((total + 255) / 256);
#define BN_CASE(CC)                                                            \
  else if (C == CC) {                                                          \
    bn_reduce1_kernel<CC><<<G, 256, 0, stream>>>(x, n, part);                  \
    bn_reduce2_kernel<CC><<<1, CC, 0, stream>>>(part, G, stats);               \
    if (res && relu)                                                           \
      bn_apply_kernel<CC, true, true><<<agrid, 256, 0, stream>>>(              \
          x, stats, gamma, beta, res, total, invn, out);                       \
    else if (relu)                                                             \
      bn_apply_kernel<CC, true, false><<<agrid, 256, 0, stream>>>(             \
          x, stats, gamma, beta, nullptr, total, invn, out);                   \
    else                                                                       \
      bn_apply_kernel<CC, false, false><<<agrid, 256, 0, stream>>>(            \
          x, stats, gamma, beta, nullptr, total, invn, out);                   \
  }
    if (false) {}
    BN_CASE(64)
    BN_CASE(128)
    BN_CASE(256)
#undef BN_CASE
  };

  float* y1 = (float*)d_out;
  float* y2 = y1 + (size_t)n1 * 64;
  float* y3 = y2 + (size_t)n2 * 128;

  // ---- stem: conv0 (k=5^3, 1->64) + BN + ReLU ----
  float* x0 = buf1;
  conv(feats, W0, im0, om0, 125, P0, n0, n0, 1, 64, x0);
  bn(x0, n0, 64, g0, b0, nullptr, true, x0);

  // ---- level 1 ----
  float* x1 = buf2;
  conv(x0, Ws1, ims1, oms1, 8, Ps1, n0, n1, 64, 64, x1);
  bn(x1, n1, 64, gs1, bs1, nullptr, true, x1);

  float* h1a = buf3;
  conv(x1, Wa1, imb1, omb1, 27, Pb1, n1, n1, 64, 64, h1a);
  bn(h1a, n1, 64, ga1, ba1, nullptr, true, h1a);

  float* h1b = buf4;
  conv(h1a, Wb1, imb1, omb1, 27, Pb1, n1, n1, 64, 64, h1b);
  bn(h1b, n1, 64, gb1, bb1, x1, true, y1);  // y1 = relu(bn(conv)+x1)

  // ---- level 2 ----
  float* x2 = buf1;
  conv(y1, Ws2, ims2, oms2, 8, Ps2, n1, n2, 64, 64, x2);
  bn(x2, n2, 64, gs2, bs2, nullptr, true, x2);

  float* res2 = buf2;
  dense(x2, Wd2, n2, 64, 128, res2);
  bn(res2, n2, 128, gd2, bd2, nullptr, false, res2);

  float* h2a = buf3;
  conv(x2, Wa2, imb2, omb2, 27, Pb2, n2, n2, 64, 128, h2a);
  bn(h2a, n2, 128, ga2, ba2, nullptr, true, h2a);

  float* h2b = buf4;
  conv(h2a, Wb2, imb2, omb2, 27, Pb2, n2, n2, 128, 128, h2b);
  bn(h2b, n2, 128, gb2, bb2, res2, true, y2);  // y2 = relu(bn(conv)+res2)

  // ---- level 3 ----
  float* x3 = buf1;
  conv(y2, Ws3, ims3, oms3, 8, Ps3, n2, n3, 128, 128, x3);
  bn(x3, n3, 128, gs3, bs3, nullptr, true, x3);

  float* res3 = buf2;
  dense(x3, Wd3, n3, 128, 256, res3);
  bn(res3, n3, 256, gd3, bd3, nullptr, false, res3);

  float* h3a = buf3;
  conv(x3, Wa3, imb3, omb3, 27, Pb3, n3, n3, 128, 256, h3a);
  bn(h3a, n3, 256, ga3, ba3, nullptr, true, h3a);

  float* h3b = buf4;
  conv(h3a, Wb3, imb3, omb3, 27, Pb3, n3, n3, 256, 256, h3b);
  bn(h3b, n3, 256, gb3, bb3, res3, true, y3);  // y3 = relu(bn(conv)+res3)
}

// Round 2
// 2195.086 us; speedup vs baseline: 4.2675x; 4.2675x over previous
//
#include <hip/hip_runtime.h>
#include <hip/hip_bf16.h>
#include <cstdint>
#include <cstddef>

typedef __attribute__((ext_vector_type(8))) short short8;
typedef __attribute__((ext_vector_type(4))) float floatx4;
typedef unsigned short ushort_t;

// ---------------------------------------------------------------------------
// ELL build: ell[out*K + k] = in  (slot unique per (out,k) -> no atomics)
// ---------------------------------------------------------------------------
__global__ void build_ell_kernel(const int* __restrict__ in_idx,
                                 const int* __restrict__ out_idx,
                                 int K, int P, int n_in, int n_out,
                                 int* __restrict__ ell) {
  int i = blockIdx.x * 256 + threadIdx.x;
  if (i >= K * P) return;
  int vin = in_idx[i];
  int vout = out_idx[i];
  if (vin < n_in && vout < n_out) {
    ell[(size_t)vout * K + (i / P)] = vin;
  }
}

// ---------------------------------------------------------------------------
// Weight pack: W[k][ci][co] f32 -> Wp[k][ci/32][co][ci%32] bf16
// B-frag load becomes one coalesced dwordx4 per lane.
// ---------------------------------------------------------------------------
__global__ void pack_w_kernel(const float* __restrict__ W,
                              __hip_bfloat16* __restrict__ Wp,
                              int K, int CIN, int COUT) {
  long i = (long)blockIdx.x * 256 + threadIdx.x;
  long tot = (long)K * CIN * COUT;
  if (i >= tot) return;
  int co = (int)(i % COUT);
  long t = i / COUT;
  int ci = (int)(t % CIN);
  int k = (int)(t / CIN);
  float v = W[((long)k * CIN + ci) * COUT + co];
  Wp[(((long)k * (CIN / 32) + (ci >> 5)) * COUT + co) * 32 + (ci & 31)] =
      __float2bfloat16(v);
}

// ---------------------------------------------------------------------------
// MFMA implicit-GEMM sparse conv. Block=256 (4 waves), BM=32 output rows.
// Wave w: row-block wr=w&1, col-half wc=w>>1. ell==nullptr -> dense (in=row).
// ---------------------------------------------------------------------------
template <int CIN, int COUT>
__global__ void conv_mfma_kernel(const ushort_t* __restrict__ xb,
                                 const ushort_t* __restrict__ Wp,
                                 const int* __restrict__ ell,
                                 int K, int n_out,
                                 float* __restrict__ out) {
  constexpr int KC = CIN / 32;
  constexpr int NT = COUT / 32;           // 16-wide col tiles per wave
  constexpr int STR = CIN + 8;            // LDS row stride (bf16), bank-spread
  __shared__ alignas(16) ushort_t xs[32 * STR];
  const int tid = threadIdx.x;
  const int lane = tid & 63;
  const int w = tid >> 6;
  const int wr = w & 1;
  const int wc = w >> 1;
  const long m0 = (long)blockIdx.x * 32;

  floatx4 acc[NT];
#pragma unroll
  for (int t = 0; t < NT; ++t) acc[t] = (floatx4){0.f, 0.f, 0.f, 0.f};

  const int arow = wr * 16 + (lane & 15);
  const int achunk = lane >> 4;           // 0..3
  const int bcolbase = wc * (COUT / 2);

  for (int k = 0; k < K; ++k) {
    int e;
    if (ell) {
      e = (lane < 32 && (m0 + lane) < n_out) ? ell[(m0 + lane) * K + k] : -1;
      if (__ballot(e >= 0) == 0ull) continue;   // uniform across block
    } else {
      e = (lane < 32 && (m0 + lane) < n_out) ? (int)(m0 + lane) : -1;
    }
    __syncthreads();  // previous iteration's LDS reads complete
    // gather 32 rows x CIN bf16 into LDS (invalid rows -> zeros)
#pragma unroll
    for (int p = 0; p < CIN / 64; ++p) {
      int base = (p * 256 + tid) * 8;
      int row = base / CIN;
      int cj = base % CIN;
      int in = __shfl(e, row);
      short8 v = (short8){0, 0, 0, 0, 0, 0, 0, 0};
      if (in >= 0) v = *(const short8*)(xb + (size_t)in * CIN + cj);
      *(short8*)(xs + row * STR + cj) = v;
    }
    __syncthreads();
    const ushort_t* wkbase = Wp + (size_t)k * KC * COUT * 32;
    for (int kc = 0; kc < KC; ++kc) {
      short8 a = *(const short8*)(xs + arow * STR + kc * 32 + achunk * 8);
      const ushort_t* bk = wkbase + (size_t)kc * COUT * 32 + achunk * 8;
#pragma unroll
      for (int t = 0; t < NT; ++t) {
        short8 b = *(const short8*)(bk + (size_t)(bcolbase + t * 16 + (lane & 15)) * 32);
        acc[t] = __builtin_amdgcn_mfma_f32_16x16x32_bf16(a, b, acc[t], 0, 0, 0);
      }
    }
  }
  // epilogue: C layout col=lane&15, row=(lane>>4)*4+r
  const int ccol = lane & 15;
  const int crow0 = (lane >> 4) * 4;
#pragma unroll
  for (int t = 0; t < NT; ++t) {
    int col = bcolbase + t * 16 + ccol;
#pragma unroll
    for (int r = 0; r < 4; ++r) {
      long row = m0 + wr * 16 + crow0 + r;
      if (row < n_out) out[row * COUT + col] = acc[t][r];
    }
  }
}

// ---------------------------------------------------------------------------
// conv0 (CIN=1) stays f32 gather.
// ---------------------------------------------------------------------------
template <int CIN, int COUT>
__global__ void gather_conv_kernel(const float* __restrict__ x,
                                   const float* __restrict__ W,
                                   const int* __restrict__ ell,
                                   int K, int n_out,
                                   float* __restrict__ out) {
  constexpr int ROWS = 256 / COUT;
  const int c = threadIdx.x % COUT;
  const int r = threadIdx.x / COUT;
  const long row = (long)blockIdx.x * ROWS + r;
  if (row >= n_out) return;
  float acc = 0.f;
  for (int k = 0; k < K; ++k) {
    const int in = ell[row * (long)K + k];
    if (in < 0) continue;
    const float* __restrict__ xr = x + (long)in * CIN;
    const float* __restrict__ wk = W + (size_t)k * CIN * COUT + c;
#pragma unroll
    for (int ci = 0; ci < CIN; ++ci)
      acc = fmaf(xr[ci], wk[(size_t)ci * COUT], acc);
  }
  out[row * (long)COUT + c] = acc;
}

// ---------------------------------------------------------------------------
// BN: deterministic two-pass stats + fused apply (residual/ReLU/bf16-out).
// ---------------------------------------------------------------------------
template <int C>
__global__ void bn_reduce1_kernel(const float* __restrict__ x, int n,
                                  float* __restrict__ part) {
  constexpr int RL = 256 / C;
  const int c = threadIdx.x % C;
  const int rl = threadIdx.x / C;
  float s = 0.f, ss = 0.f;
  for (long row = (long)blockIdx.x * RL + rl; row < n;
       row += (long)gridDim.x * RL) {
    float v = x[row * C + c];
    s += v;
    ss += v * v;
  }
  __shared__ float sh[512];
  sh[threadIdx.x] = s;
  sh[256 + threadIdx.x] = ss;
  __syncthreads();
  if (rl == 0) {
#pragma unroll
    for (int j = 1; j < RL; ++j) {
      s += sh[j * C + c];
      ss += sh[256 + j * C + c];
    }
    part[(size_t)blockIdx.x * 2 * C + c] = s;
    part[(size_t)blockIdx.x * 2 * C + C + c] = ss;
  }
}

template <int C>
__global__ void bn_reduce2_kernel(const float* __restrict__ part, int G,
                                  float* __restrict__ stats) {
  const int c = threadIdx.x;
  float s = 0.f, ss = 0.f;
  for (int g = 0; g < G; ++g) {
    s += part[(size_t)g * 2 * C + c];
    ss += part[(size_t)g * 2 * C + C + c];
  }
  stats[c] = s;
  stats[C + c] = ss;
}

template <int C, bool RELU, bool RES>
__global__ void bn_apply_kernel(const float* __restrict__ x,
                                const float* __restrict__ stats,
                                const float* __restrict__ gamma,
                                const float* __restrict__ beta,
                                const float* __restrict__ res,
                                long total, float inv_n,
                                float* __restrict__ out,
                                __hip_bfloat16* __restrict__ outb) {
  long i = (long)blockIdx.x * 256 + threadIdx.x;
  if (i >= total) return;
  const int c = (int)(i % C);
  const float m = stats[c] * inv_n;
  const float var = stats[C + c] * inv_n - m * m;
  const float sc = rsqrtf(var + 1e-5f) * gamma[c];
  float v = (x[i] - m) * sc + beta[c];
  if (RES) v += res[i];
  if (RELU) v = fmaxf(v, 0.f);
  out[i] = v;
  if (outb) outb[i] = __float2bfloat16(v);
}

// ---------------------------------------------------------------------------

extern "C" void kernel_launch(void* const* d_in, const int* in_sizes, int n_in,
                              void* d_out, int out_size, void* d_ws,
                              size_t ws_size, hipStream_t stream) {
  const float* feats = (const float*)d_in[0];
  const float* W0  = (const float*)d_in[1];
  const float* g0  = (const float*)d_in[2];
  const float* b0  = (const float*)d_in[3];
  const float* Ws1 = (const float*)d_in[4];
  const float* gs1 = (const float*)d_in[5];
  const float* bs1 = (const float*)d_in[6];
  const float* Wa1 = (const float*)d_in[7];
  const float* ga1 = (const float*)d_in[8];
  const float* ba1 = (const float*)d_in[9];
  const float* Wb1 = (const float*)d_in[10];
  const float* gb1 = (const float*)d_in[11];
  const float* bb1 = (const float*)d_in[12];
  const float* Ws2 = (const float*)d_in[13];
  const float* gs2 = (const float*)d_in[14];
  const float* bs2 = (const float*)d_in[15];
  const float* Wa2 = (const float*)d_in[16];
  const float* ga2 = (const float*)d_in[17];
  const float* ba2 = (const float*)d_in[18];
  const float* Wb2 = (const float*)d_in[19];
  const float* gb2 = (const float*)d_in[20];
  const float* bb2 = (const float*)d_in[21];
  const float* Wd2 = (const float*)d_in[22];
  const float* gd2 = (const float*)d_in[23];
  const float* bd2 = (const float*)d_in[24];
  const float* Ws3 = (const float*)d_in[25];
  const float* gs3 = (const float*)d_in[26];
  const float* bs3 = (const float*)d_in[27];
  const float* Wa3 = (const float*)d_in[28];
  const float* ga3 = (const float*)d_in[29];
  const float* ba3 = (const float*)d_in[30];
  const float* Wb3 = (const float*)d_in[31];
  const float* gb3 = (const float*)d_in[32];
  const float* bb3 = (const float*)d_in[33];
  const float* Wd3 = (const float*)d_in[34];
  const float* gd3 = (const float*)d_in[35];
  const float* bd3 = (const float*)d_in[36];
  const int* im0  = (const int*)d_in[40];
  const int* om0  = (const int*)d_in[41];
  const int* ims1 = (const int*)d_in[42];
  const int* oms1 = (const int*)d_in[43];
  const int* imb1 = (const int*)d_in[44];
  const int* omb1 = (const int*)d_in[45];
  const int* ims2 = (const int*)d_in[46];
  const int* oms2 = (const int*)d_in[47];
  const int* imb2 = (const int*)d_in[48];
  const int* omb2 = (const int*)d_in[49];
  const int* ims3 = (const int*)d_in[50];
  const int* oms3 = (const int*)d_in[51];
  const int* imb3 = (const int*)d_in[52];
  const int* omb3 = (const int*)d_in[53];

  const int n0 = in_sizes[0];
  const int n1 = in_sizes[37] / 3;
  const int n2 = in_sizes[38] / 3;
  const int n3 = in_sizes[39] / 3;
  const int P0  = in_sizes[40] / 125;
  const int Ps1 = in_sizes[42] / 8;
  const int Pb1 = in_sizes[44] / 27;
  const int Ps2 = in_sizes[46] / 8;
  const int Pb2 = in_sizes[48] / 27;
  const int Ps3 = in_sizes[50] / 8;
  const int Pb3 = in_sizes[52] / 27;

  // ---- workspace carve ----
  char* w = (char*)d_ws;
  auto carve = [&](size_t bytes) {
    char* p = w;
    w += (bytes + 255) & ~(size_t)255;
    return p;
  };
  auto maxsz = [](size_t a, size_t b) { return a > b ? a : b; };
  size_t ellElems = maxsz((size_t)n0 * 125, (size_t)n1 * 27);
  int* ell = (int*)carve(ellElems * sizeof(int));
  float* part = (float*)carve((size_t)256 * 512 * sizeof(float));
  float* stats = (float*)carve((size_t)512 * sizeof(float));
  size_t capE = (size_t)n0 * 64;  // largest feature map (elems)
  float* buf1 = (float*)carve(capE * sizeof(float));
  float* buf2 = (float*)carve(capE * sizeof(float));
  float* buf3 = (float*)carve(capE * sizeof(float));
  __hip_bfloat16* bbA = (__hip_bfloat16*)carve(capE * 2);
  __hip_bfloat16* bbB = (__hip_bfloat16*)carve(capE * 2);
  __hip_bfloat16* bbC = (__hip_bfloat16*)carve(capE * 2);
  (void)ws_size;

  // ---- weight packing ----
  auto pack = [&](const float* W, int K, int cin, int cout) {
    __hip_bfloat16* Wp = (__hip_bfloat16*)carve((size_t)K * cin * cout * 2);
    long tot = (long)K * cin * cout;
    pack_w_kernel<<<(int)((tot + 255) / 256), 256, 0, stream>>>(W, Wp, K, cin,
                                                                cout);
    return Wp;
  };
  __hip_bfloat16* Ps1p = pack(Ws1, 8, 64, 64);
  __hip_bfloat16* Pa1p = pack(Wa1, 27, 64, 64);
  __hip_bfloat16* Pb1p = pack(Wb1, 27, 64, 64);
  __hip_bfloat16* Ps2p = pack(Ws2, 8, 64, 64);
  __hip_bfloat16* Pd2p = pack(Wd2, 1, 64, 128);
  __hip_bfloat16* Pa2p = pack(Wa2, 27, 64, 128);
  __hip_bfloat16* Pb2p = pack(Wb2, 27, 128, 128);
  __hip_bfloat16* Ps3p = pack(Ws3, 8, 128, 128);
  __hip_bfloat16* Pd3p = pack(Wd3, 1, 128, 256);
  __hip_bfloat16* Pa3p = pack(Wa3, 27, 128, 256);
  __hip_bfloat16* Pb3p = pack(Wb3, 27, 256, 256);

  // ---- helpers ----
  auto convm = [&](const __hip_bfloat16* xbuf, const __hip_bfloat16* Wp,
                   const int* im, const int* om, int K, int P, int nin,
                   int nout, int cin, int cout, float* outp, bool useEll) {
    const int* ellp = nullptr;
    if (useEll) {
      hipMemsetAsync(ell, 0xFF, (size_t)nout * K * sizeof(int), stream);
      int tot = K * P;
      build_ell_kernel<<<(tot + 255) / 256, 256, 0, stream>>>(im, om, K, P,
                                                              nin, nout, ell);
      ellp = ell;
    }
    int grid = (nout + 31) / 32;
#define CM_CASE(CI, CO)                                                        \
  else if (cin == CI && cout == CO) {                                          \
    conv_mfma_kernel<CI, CO><<<grid, 256, 0, stream>>>(                        \
        (const ushort_t*)xbuf, (const ushort_t*)Wp, ellp, K, nout, outp);      \
  }
    if (false) {}
    CM_CASE(64, 64)
    CM_CASE(64, 128)
    CM_CASE(128, 128)
    CM_CASE(128, 256)
    CM_CASE(256, 256)
#undef CM_CASE
  };

  auto bn = [&](const float* x, int n, int C, const float* gamma,
                const float* beta, const float* res, bool relu, float* outp,
                __hip_bfloat16* outb) {
    const int G = 256;
    float invn = 1.0f / (float)n;
    long total = (long)n * C;
    int agrid = (int)((total + 255) / 256);
#define BN_CASE(CC)                                                            \
  else if (C == CC) {                                                          \
    bn_reduce1_kernel<CC><<<G, 256, 0, stream>>>(x, n, part);                  \
    bn_reduce2_kernel<CC><<<1, CC, 0, stream>>>(part, G, stats);               \
    if (res && relu)                                                           \
      bn_apply_kernel<CC, true, true><<<agrid, 256, 0, stream>>>(              \
          x, stats, gamma, beta, res, total, invn, outp, outb);                \
    else if (relu)                                                             \
      bn_apply_kernel<CC, true, false><<<agrid, 256, 0, stream>>>(             \
          x, stats, gamma, beta, nullptr, total, invn, outp, outb);            \
    else                                                                       \
      bn_apply_kernel<CC, false, false><<<agrid, 256, 0, stream>>>(            \
          x, stats, gamma, beta, nullptr, total, invn, outp, outb);            \
  }
    if (false) {}
    BN_CASE(64)
    BN_CASE(128)
    BN_CASE(256)
#undef BN_CASE
  };

  float* y1 = (float*)d_out;
  float* y2 = y1 + (size_t)n1 * 64;
  float* y3 = y2 + (size_t)n2 * 128;

  // ---- stem: conv0 (k=125, 1->64) f32 + BN -> x0 (f32 buf1, bf16 bbA) ----
  {
    hipMemsetAsync(ell, 0xFF, (size_t)n0 * 125 * sizeof(int), stream);
    int tot = 125 * P0;
    build_ell_kernel<<<(tot + 255) / 256, 256, 0, stream>>>(im0, om0, 125, P0,
                                                            n0, n0, ell);
    int grid = (n0 + 3) / 4;  // ROWS = 256/64 = 4
    gather_conv_kernel<1, 64><<<grid, 256, 0, stream>>>(feats, W0, ell, 125,
                                                        n0, buf1);
  }
  bn(buf1, n0, 64, g0, b0, nullptr, true, buf1, bbA);

  // ---- level 1 ----
  convm(bbA, Ps1p, ims1, oms1, 8, Ps1, n0, n1, 64, 64, buf2, true);
  bn(buf2, n1, 64, gs1, bs1, nullptr, true, buf2, bbB);           // x1
  convm(bbB, Pa1p, imb1, omb1, 27, Pb1, n1, n1, 64, 64, buf3, true);
  bn(buf3, n1, 64, ga1, ba1, nullptr, true, buf3, bbC);           // h1a
  convm(bbC, Pb1p, imb1, omb1, 27, Pb1, n1, n1, 64, 64, buf1, true);
  bn(buf1, n1, 64, gb1, bb1, buf2, true, y1, bbA);                // y1

  // ---- level 2 ----
  convm(bbA, Ps2p, ims2, oms2, 8, Ps2, n1, n2, 64, 64, buf3, true);
  bn(buf3, n2, 64, gs2, bs2, nullptr, true, buf3, bbB);           // x2
  convm(bbB, Pd2p, nullptr, nullptr, 1, 0, n2, n2, 64, 128, buf1, false);
  bn(buf1, n2, 128, gd2, bd2, nullptr, false, buf1, nullptr);     // res2
  convm(bbB, Pa2p, imb2, omb2, 27, Pb2, n2, n2, 64, 128, buf2, true);
  bn(buf2, n2, 128, ga2, ba2, nullptr, true, buf2, bbC);          // h2a
  convm(bbC, Pb2p, imb2, omb2, 27, Pb2, n2, n2, 128, 128, buf3, true);
  bn(buf3, n2, 128, gb2, bb2, buf1, true, y2, bbA);               // y2

  // ---- level 3 ----
  convm(bbA, Ps3p, ims3, oms3, 8, Ps3, n2, n3, 128, 128, buf2, true);
  bn(buf2, n3, 128, gs3, bs3, nullptr, true, buf2, bbB);          // x3
  convm(bbB, Pd3p, nullptr, nullptr, 1, 0, n3, n3, 128, 256, buf1, false);
  bn(buf1, n3, 256, gd3, bd3, nullptr, false, buf1, nullptr);     // res3
  convm(bbB, Pa3p, imb3, omb3, 27, Pb3, n3, n3, 128, 256, buf3, true);
  bn(buf3, n3, 256, ga3, ba3, nullptr, true, buf3, bbC);          // h3a
  convm(bbC, Pb3p, imb3, omb3, 27, Pb3, n3, n3, 256, 256, buf2, true);
  bn(buf2, n3, 256, gb3, bb3, buf1, true, y3, nullptr);           // y3
}

// Round 3
// 1772.728 us; speedup vs baseline: 5.2843x; 1.2383x over previous
//
#include <hip/hip_runtime.h>
#include <hip/hip_bf16.h>
#include <cstdint>
#include <cstddef>

typedef __attribute__((ext_vector_type(8))) short sh8;
typedef __attribute__((ext_vector_type(4))) short sh4;
typedef __attribute__((ext_vector_type(4))) int ix4;
typedef __attribute__((ext_vector_type(16))) float floatx16;
typedef unsigned short ushort_t;

// ---------------------------------------------------------------------------
// ELL build: ell[out*S + k] = in  (slot unique per (out,k) -> no atomics)
// ---------------------------------------------------------------------------
__global__ void build_ell_kernel(const int* __restrict__ in_idx,
                                 const int* __restrict__ out_idx,
                                 int K, int S, int P, int n_in, int n_out,
                                 int* __restrict__ ell) {
  int i = blockIdx.x * 256 + threadIdx.x;
  if (i >= K * P) return;
  int vin = in_idx[i];
  int vout = out_idx[i];
  if (vin < n_in && vout < n_out) {
    ell[(size_t)vout * S + (i / P)] = vin;
  }
}

// ---------------------------------------------------------------------------
// Weight pack for 32x32x16 frags: W[k][ci][co] f32 -> Wp[k][ci/16][co][ci%16]
// ---------------------------------------------------------------------------
__global__ void pack_w_kernel(const float* __restrict__ W,
                              __hip_bfloat16* __restrict__ Wp,
                              int K, int CIN, int COUT) {
  long i = (long)blockIdx.x * 256 + threadIdx.x;
  long tot = (long)K * CIN * COUT;
  if (i >= tot) return;
  int co = (int)(i % COUT);
  long t = i / COUT;
  int ci = (int)(t % CIN);
  int k = (int)(t / CIN);
  float v = W[((long)k * CIN + ci) * COUT + co];
  Wp[(((long)k * (CIN / 16) + (ci >> 4)) * COUT + co) * 16 + (ci & 15)] =
      __float2bfloat16(v);
}

// conv0 weights: W0[125][1][64] -> Wp0[k/16][co][k%16], k padded to 128.
__global__ void pack_w0_kernel(const float* __restrict__ W,
                               __hip_bfloat16* __restrict__ Wp) {
  int i = blockIdx.x * 256 + threadIdx.x;
  if (i >= 128 * 64) return;
  int co = i & 63;
  int ki = i >> 6;
  float v = (ki < 125) ? W[ki * 64 + co] : 0.f;
  Wp[(((ki >> 4) * 64) + co) * 16 + (ki & 15)] = __float2bfloat16(v);
}

// feats f32 -> bf16 with one zero pad element at the end.
__global__ void f2bf_kernel(const float* __restrict__ x,
                            __hip_bfloat16* __restrict__ y, long n, long npad) {
  long i = (long)blockIdx.x * 256 + threadIdx.x;
  if (i >= npad) return;
  y[i] = __float2bfloat16(i < n ? x[i] : 0.f);
}

// ---------------------------------------------------------------------------
// conv0: out[n0][64] = gatherA(x1ch, ell[*,128]) @ W0  via 32x32x16 MFMA.
// Block 256 = 4 waves (2M x 2N), BM=64 rows.
// ---------------------------------------------------------------------------
__global__ __launch_bounds__(256, 2) void conv0_mfma_kernel(
    const ushort_t* __restrict__ xpad,   // [n0+1] bf16, [n0]=0
    const ushort_t* __restrict__ Wp0,    // [8][64][16]
    const int* __restrict__ ell,         // [n0][128]
    int n_out, float* __restrict__ out) {
  constexpr int STR = 136;
  __shared__ ushort_t xs[64 * STR];
  const int tid = threadIdx.x;
  const int lane = tid & 63;
  const int wv = tid >> 6;
  const int wm = wv & 1, wn = wv >> 1;
  const long m0 = (long)blockIdx.x * 64;
  const int row = tid >> 2;
  const int kk0 = (tid & 3) * 32;
  const long grow = m0 + row;

  if (grow < n_out) {
    const ix4* ep = (const ix4*)(ell + grow * 128 + kk0);
#pragma unroll
    for (int g = 0; g < 8; ++g) {
      ix4 e = ep[g];
      sh4 v;
#pragma unroll
      for (int j = 0; j < 4; ++j) {
        int ix = (e[j] < 0) ? n_out : e[j];
        v[j] = (short)xpad[ix];
      }
      *(sh4*)(&xs[row * STR + kk0 + g * 4]) = v;
    }
  } else {
    sh4 z = (sh4)(short)0;
#pragma unroll
    for (int g = 0; g < 8; ++g) *(sh4*)(&xs[row * STR + kk0 + g * 4]) = z;
  }
  __syncthreads();

  const int arow = wm * 32 + (lane & 31);
  const int koff = (lane >> 5) * 8;
  const int bcol = wn * 32 + (lane & 31);
  floatx16 acc = (floatx16)(0.0f);
#pragma unroll
  for (int kc = 0; kc < 8; ++kc) {
    sh8 a = *(const sh8*)(&xs[arow * STR + kc * 16 + koff]);
    sh8 b = *(const sh8*)(Wp0 + ((size_t)kc * 64 + bcol) * 16 + koff);
    acc = __builtin_amdgcn_mfma_f32_32x32x16_bf16(a, b, acc, 0, 0, 0);
  }
  const int lrow = (lane >> 5) * 4;
#pragma unroll
  for (int r = 0; r < 16; ++r) {
    long orow = m0 + wm * 32 + (r & 3) + 8 * (r >> 2) + lrow;
    if (orow < n_out) out[orow * 64 + bcol] = acc[r];
  }
}

// ---------------------------------------------------------------------------
// Main MFMA implicit-GEMM sparse conv. Block 256 = 4 waves (2M x 2N), BM=64.
// Double-buffered LDS A staging with issue-early/write-late reg prefetch.
// ell==nullptr -> dense 1x1 (in = row). xb has a zero pad row at n_in.
// ---------------------------------------------------------------------------
template <int CIN, int COUT>
__global__ __launch_bounds__(256, 2) void conv_mfma_kernel(
    const ushort_t* __restrict__ xb, const ushort_t* __restrict__ Wp,
    const int* __restrict__ ell, int K, int n_out, int n_in,
    float* __restrict__ out) {
  constexpr int KC = CIN / 16;    // k-chunks of 16
  constexpr int NT = COUT / 64;   // 32-col frags per wave
  constexpr int STR = CIN + 8;
  constexpr int CH = CIN / 32;    // sh8 chunks per thread for staging
  __shared__ ushort_t xs[2][64 * STR];
  const int tid = threadIdx.x;
  const int lane = tid & 63;
  const int wv = tid >> 6;
  const int wm = wv & 1, wn = wv >> 1;
  const long m0 = (long)blockIdx.x * 64;
  const int srow = tid >> 2;
  const int scol = (tid & 3) * (CIN / 4);
  const long grow = m0 + srow;

  floatx16 acc[NT];
#pragma unroll
  for (int t = 0; t < NT; ++t) acc[t] = (floatx16)(0.0f);

  sh8 sreg[CH];
  auto issue = [&](int k) {
    int in = n_in;  // pad row (zeros)
    if (grow < n_out) {
      int e = ell ? ell[grow * K + k] : (int)grow;
      if (e >= 0) in = e;
    }
    const ushort_t* src = xb + (size_t)in * CIN + scol;
#pragma unroll
    for (int c = 0; c < CH; ++c) sreg[c] = *(const sh8*)(src + c * 8);
  };
  auto commit = [&](int buf) {
    ushort_t* dst = &xs[buf][srow * STR + scol];
#pragma unroll
    for (int c = 0; c < CH; ++c) *(sh8*)(dst + c * 8) = sreg[c];
  };

  issue(0);
  commit(0);
  __syncthreads();

  const int arow = wm * 32 + (lane & 31);
  const int koff = (lane >> 5) * 8;
  const int bcol = wn * (COUT / 2) + (lane & 31);
  for (int k = 0; k < K; ++k) {
    const int cur = k & 1;
    if (k + 1 < K) issue(k + 1);  // global loads in flight under compute
    sh8 a[KC];
#pragma unroll
    for (int kc = 0; kc < KC; ++kc)
      a[kc] = *(const sh8*)(&xs[cur][arow * STR + kc * 16 + koff]);
    const ushort_t* wk = Wp + ((size_t)k * KC * COUT + bcol) * 16 + koff;
#pragma unroll
    for (int t = 0; t < NT; ++t) {
#pragma unroll
      for (int kc = 0; kc < KC; ++kc) {
        sh8 b = *(const sh8*)(wk + ((size_t)kc * COUT + t * 32) * 16);
        acc[t] =
            __builtin_amdgcn_mfma_f32_32x32x16_bf16(a[kc], b, acc[t], 0, 0, 0);
      }
    }
    if (k + 1 < K) {
      __syncthreads();       // all waves done reading xs[cur^1] (step k-1)
      commit(cur ^ 1);
      __syncthreads();       // writes visible before step k+1 reads
    }
  }

  const int ccol = wn * (COUT / 2) + (lane & 31);
  const int lrowb = wm * 32 + (lane >> 5) * 4;
#pragma unroll
  for (int t = 0; t < NT; ++t) {
#pragma unroll
    for (int r = 0; r < 16; ++r) {
      long row = m0 + lrowb + (r & 3) + 8 * (r >> 2);
      if (row < n_out) out[row * COUT + ccol + t * 32] = acc[t][r];
    }
  }
}

// ---------------------------------------------------------------------------
// BN: deterministic two-pass stats + fused apply (residual/ReLU/bf16 + pad).
// ---------------------------------------------------------------------------
template <int C>
__global__ void bn_reduce1_kernel(const float* __restrict__ x, int n,
                                  float* __restrict__ part) {
  constexpr int RL = 256 / C;
  const int c = threadIdx.x % C;
  const int rl = threadIdx.x / C;
  float s = 0.f, ss = 0.f;
  for (long row = (long)blockIdx.x * RL + rl; row < n;
       row += (long)gridDim.x * RL) {
    float v = x[row * C + c];
    s += v;
    ss += v * v;
  }
  __shared__ float sh[512];
  sh[threadIdx.x] = s;
  sh[256 + threadIdx.x] = ss;
  __syncthreads();
  if (rl == 0) {
#pragma unroll
    for (int j = 1; j < RL; ++j) {
      s += sh[j * C + c];
      ss += sh[256 + j * C + c];
    }
    part[(size_t)blockIdx.x * 2 * C + c] = s;
    part[(size_t)blockIdx.x * 2 * C + C + c] = ss;
  }
}

template <int C>
__global__ void bn_reduce2_kernel(const float* __restrict__ part, int G,
                                  float* __restrict__ stats) {
  const int c = threadIdx.x;
  float s = 0.f, ss = 0.f;
  for (int g = 0; g < G; ++g) {
    s += part[(size_t)g * 2 * C + c];
    ss += part[(size_t)g * 2 * C + C + c];
  }
  stats[c] = s;
  stats[C + c] = ss;
}

template <int C, bool RELU, bool RES>
__global__ void bn_apply_kernel(const float* __restrict__ x,
                                const float* __restrict__ stats,
                                const float* __restrict__ gamma,
                                const float* __restrict__ beta,
                                const float* __restrict__ res,
                                long total, float inv_n,
                                float* __restrict__ out,
                                __hip_bfloat16* __restrict__ outb) {
  long i = (long)blockIdx.x * 256 + threadIdx.x;
  if (i >= total) {
    if (outb && i < total + C) outb[i] = __float2bfloat16(0.f);  // pad row
    return;
  }
  const int c = (int)(i % C);
  const float m = stats[c] * inv_n;
  const float var = stats[C + c] * inv_n - m * m;
  const float sc = rsqrtf(var + 1e-5f) * gamma[c];
  float v = (x[i] - m) * sc + beta[c];
  if (RES) v += res[i];
  if (RELU) v = fmaxf(v, 0.f);
  out[i] = v;
  if (outb) outb[i] = __float2bfloat16(v);
}

// ---------------------------------------------------------------------------

extern "C" void kernel_launch(void* const* d_in, const int* in_sizes, int n_in,
                              void* d_out, int out_size, void* d_ws,
                              size_t ws_size, hipStream_t stream) {
  const float* feats = (const float*)d_in[0];
  const float* W0  = (const float*)d_in[1];
  const float* g0  = (const float*)d_in[2];
  const float* b0  = (const float*)d_in[3];
  const float* Ws1 = (const float*)d_in[4];
  const float* gs1 = (const float*)d_in[5];
  const float* bs1 = (const float*)d_in[6];
  const float* Wa1 = (const float*)d_in[7];
  const float* ga1 = (const float*)d_in[8];
  const float* ba1 = (const float*)d_in[9];
  const float* Wb1 = (const float*)d_in[10];
  const float* gb1 = (const float*)d_in[11];
  const float* bb1 = (const float*)d_in[12];
  const float* Ws2 = (const float*)d_in[13];
  const float* gs2 = (const float*)d_in[14];
  const float* bs2 = (const float*)d_in[15];
  const float* Wa2 = (const float*)d_in[16];
  const float* ga2 = (const float*)d_in[17];
  const float* ba2 = (const float*)d_in[18];
  const float* Wb2 = (const float*)d_in[19];
  const float* gb2 = (const float*)d_in[20];
  const float* bb2 = (const float*)d_in[21];
  const float* Wd2 = (const float*)d_in[22];
  const float* gd2 = (const float*)d_in[23];
  const float* bd2 = (const float*)d_in[24];
  const float* Ws3 = (const float*)d_in[25];
  const float* gs3 = (const float*)d_in[26];
  const float* bs3 = (const float*)d_in[27];
  const float* Wa3 = (const float*)d_in[28];
  const float* ga3 = (const float*)d_in[29];
  const float* ba3 = (const float*)d_in[30];
  const float* Wb3 = (const float*)d_in[31];
  const float* gb3 = (const float*)d_in[32];
  const float* bb3 = (const float*)d_in[33];
  const float* Wd3 = (const float*)d_in[34];
  const float* gd3 = (const float*)d_in[35];
  const float* bd3 = (const float*)d_in[36];
  const int* im0  = (const int*)d_in[40];
  const int* om0  = (const int*)d_in[41];
  const int* ims1 = (const int*)d_in[42];
  const int* oms1 = (const int*)d_in[43];
  const int* imb1 = (const int*)d_in[44];
  const int* omb1 = (const int*)d_in[45];
  const int* ims2 = (const int*)d_in[46];
  const int* oms2 = (const int*)d_in[47];
  const int* imb2 = (const int*)d_in[48];
  const int* omb2 = (const int*)d_in[49];
  const int* ims3 = (const int*)d_in[50];
  const int* oms3 = (const int*)d_in[51];
  const int* imb3 = (const int*)d_in[52];
  const int* omb3 = (const int*)d_in[53];

  const int n0 = in_sizes[0];
  const int n1 = in_sizes[37] / 3;
  const int n2 = in_sizes[38] / 3;
  const int n3 = in_sizes[39] / 3;
  const int P0  = in_sizes[40] / 125;
  const int Ps1 = in_sizes[42] / 8;
  const int Pb1 = in_sizes[44] / 27;
  const int Ps2 = in_sizes[46] / 8;
  const int Pb2 = in_sizes[48] / 27;
  const int Ps3 = in_sizes[50] / 8;
  const int Pb3 = in_sizes[52] / 27;

  // ---- workspace carve ----
  char* w = (char*)d_ws;
  auto carve = [&](size_t bytes) {
    char* p = w;
    w += (bytes + 255) & ~(size_t)255;
    return p;
  };
  int* ellS = (int*)carve((size_t)n0 * 128 * sizeof(int));
  int* ellB = (int*)carve((size_t)n1 * 27 * sizeof(int));
  float* part = (float*)carve((size_t)256 * 512 * sizeof(float));
  float* stats = (float*)carve((size_t)512 * sizeof(float));
  size_t capE = (size_t)n0 * 64 + 256;  // + pad row
  float* buf1 = (float*)carve(capE * sizeof(float));
  float* buf2 = (float*)carve(capE * sizeof(float));
  float* buf3 = (float*)carve(capE * sizeof(float));
  __hip_bfloat16* bbA = (__hip_bfloat16*)carve(capE * 2);
  __hip_bfloat16* bbB = (__hip_bfloat16*)carve(capE * 2);
  __hip_bfloat16* bbC = (__hip_bfloat16*)carve(capE * 2);
  __hip_bfloat16* xfeat = (__hip_bfloat16*)carve(((size_t)n0 + 1) * 2);
  (void)ws_size;

  // ---- weight packing ----
  auto pack = [&](const float* W, int K, int cin, int cout) {
    __hip_bfloat16* Wp = (__hip_bfloat16*)carve((size_t)K * cin * cout * 2);
    long tot = (long)K * cin * cout;
    pack_w_kernel<<<(int)((tot + 255) / 256), 256, 0, stream>>>(W, Wp, K, cin,
                                                                cout);
    return Wp;
  };
  __hip_bfloat16* Wp0 = (__hip_bfloat16*)carve((size_t)128 * 64 * 2);
  pack_w0_kernel<<<32, 256, 0, stream>>>(W0, Wp0);
  __hip_bfloat16* Ps1p = pack(Ws1, 8, 64, 64);
  __hip_bfloat16* Pa1p = pack(Wa1, 27, 64, 64);
  __hip_bfloat16* Pb1p = pack(Wb1, 27, 64, 64);
  __hip_bfloat16* Ps2p = pack(Ws2, 8, 64, 64);
  __hip_bfloat16* Pd2p = pack(Wd2, 1, 64, 128);
  __hip_bfloat16* Pa2p = pack(Wa2, 27, 64, 128);
  __hip_bfloat16* Pb2p = pack(Wb2, 27, 128, 128);
  __hip_bfloat16* Ps3p = pack(Ws3, 8, 128, 128);
  __hip_bfloat16* Pd3p = pack(Wd3, 1, 128, 256);
  __hip_bfloat16* Pa3p = pack(Wa3, 27, 128, 256);
  __hip_bfloat16* Pb3p = pack(Wb3, 27, 256, 256);

  f2bf_kernel<<<(int)((n0 + 256) / 256), 256, 0, stream>>>(feats, xfeat, n0,
                                                           n0 + 1);

  auto buildEll = [&](int* ellbuf, const int* im, const int* om, int K, int S,
                      int P, int nin, int nout) {
    hipMemsetAsync(ellbuf, 0xFF, (size_t)nout * S * sizeof(int), stream);
    int tot = K * P;
    build_ell_kernel<<<(tot + 255) / 256, 256, 0, stream>>>(im, om, K, S, P,
                                                            nin, nout, ellbuf);
  };

  auto convm = [&](const __hip_bfloat16* xb, const __hip_bfloat16* Wp,
                   const int* ellp, int K, int nout, int nin, int cin,
                   int cout, float* outp) {
    int grid = (nout + 63) / 64;
#define CM_CASE(CI, CO)                                                        \
  else if (cin == CI && cout == CO) {                                          \
    conv_mfma_kernel<CI, CO><<<grid, 256, 0, stream>>>(                        \
        (const ushort_t*)xb, (const ushort_t*)Wp, ellp, K, nout, nin, outp);   \
  }
    if (false) {}
    CM_CASE(64, 64)
    CM_CASE(64, 128)
    CM_CASE(128, 128)
    CM_CASE(128, 256)
    CM_CASE(256, 256)
#undef CM_CASE
  };

  auto bn = [&](const float* x, int n, int C, const float* gamma,
                const float* beta, const float* res, bool relu, float* outp,
                __hip_bfloat16* outb) {
    const int G = 256;
    float invn = 1.0f / (float)n;
    long total = (long)n * C;
    int agrid = (int)((total + C + 255) / 256);
#define BN_CASE(CC)                                                            \
  else if (C == CC) {                                                          \
    bn_reduce1_kernel<CC><<<G, 256, 0, stream>>>(x, n, part);                  \
    bn_reduce2_kernel<CC><<<1, CC, 0, stream>>>(part, G, stats);               \
    if (res && relu)                                                           \
      bn_apply_kernel<CC, true, true><<<agrid, 256, 0, stream>>>(              \
          x, stats, gamma, beta, res, total, invn, outp, outb);                \
    else if (relu)                                                             \
      bn_apply_kernel<CC, true, false><<<agrid, 256, 0, stream>>>(             \
          x, stats, gamma, beta, nullptr, total, invn, outp, outb);            \
    else                                                                       \
      bn_apply_kernel<CC, false, false><<<agrid, 256, 0, stream>>>(            \
          x, stats, gamma, beta, nullptr, total, invn, outp, outb);            \
  }
    if (false) {}
    BN_CASE(64)
    BN_CASE(128)
    BN_CASE(256)
#undef BN_CASE
  };

  float* y1 = (float*)d_out;
  float* y2 = y1 + (size_t)n1 * 64;
  float* y3 = y2 + (size_t)n2 * 128;

  // ---- stem: conv0 (k=125 -> GEMM over K=128) + BN ----
  buildEll(ellS, im0, om0, 125, 128, P0, n0, n0);
  conv0_mfma_kernel<<<(n0 + 63) / 64, 256, 0, stream>>>(
      (const ushort_t*)xfeat, (const ushort_t*)Wp0, ellS, n0, buf1);
  bn(buf1, n0, 64, g0, b0, nullptr, true, buf1, bbA);               // x0

  // ---- level 1 ----
  buildEll(ellS, ims1, oms1, 8, 8, Ps1, n0, n1);
  convm(bbA, Ps1p, ellS, 8, n1, n0, 64, 64, buf2);
  bn(buf2, n1, 64, gs1, bs1, nullptr, true, buf2, bbB);             // x1
  buildEll(ellB, imb1, omb1, 27, 27, Pb1, n1, n1);
  convm(bbB, Pa1p, ellB, 27, n1, n1, 64, 64, buf3);
  bn(buf3, n1, 64, ga1, ba1, nullptr, true, buf3, bbC);             // h1a
  convm(bbC, Pb1p, ellB, 27, n1, n1, 64, 64, buf1);
  bn(buf1, n1, 64, gb1, bb1, buf2, true, y1, bbA);                  // y1

  // ---- level 2 ----
  buildEll(ellS, ims2, oms2, 8, 8, Ps2, n1, n2);
  convm(bbA, Ps2p, ellS, 8, n2, n1, 64, 64, buf3);
  bn(buf3, n2, 64, gs2, bs2, nullptr, true, buf3, bbB);             // x2
  convm(bbB, Pd2p, nullptr, 1, n2, n2, 64, 128, buf1);
  bn(buf1, n2, 128, gd2, bd2, nullptr, false, buf1, nullptr);       // res2
  buildEll(ellB, imb2, omb2, 27, 27, Pb2, n2, n2);
  convm(bbB, Pa2p, ellB, 27, n2, n2, 64, 128, buf2);
  bn(buf2, n2, 128, ga2, ba2, nullptr, true, buf2, bbC);            // h2a
  convm(bbC, Pb2p, ellB, 27, n2, n2, 128, 128, buf3);
  bn(buf3, n2, 128, gb2, bb2, buf1, true, y2, bbA);                 // y2

  // ---- level 3 ----
  buildEll(ellS, ims3, oms3, 8, 8, Ps3, n2, n3);
  convm(bbA, Ps3p, ellS, 8, n3, n2, 128, 128, buf2);
  bn(buf2, n3, 128, gs3, bs3, nullptr, true, buf2, bbB);            // x3
  convm(bbB, Pd3p, nullptr, 1, n3, n3, 128, 256, buf1);
  bn(buf1, n3, 256, gd3, bd3, nullptr, false, buf1, nullptr);       // res3
  buildEll(ellB, imb3, omb3, 27, 27, Pb3, n3, n3);
  convm(bbB, Pa3p, ellB, 27, n3, n3, 128, 256, buf3);
  bn(buf3, n3, 256, ga3, ba3, nullptr, true, buf3, bbC);            // h3a
  convm(bbC, Pb3p, ellB, 27, n3, n3, 256, 256, buf2);
  bn(buf2, n3, 256, gb3, bb3, buf1, true, y3, nullptr);             // y3
}

// Round 4
// 1567.442 us; speedup vs baseline: 5.9764x; 1.1310x over previous
//
#include <hip/hip_runtime.h>
#include <hip/hip_bf16.h>
#include <cstdint>
#include <cstddef>

typedef __attribute__((ext_vector_type(8))) short sh8;
typedef __attribute__((ext_vector_type(4))) short sh4;
typedef __attribute__((ext_vector_type(4))) int ix4;
typedef __attribute__((ext_vector_type(16))) float floatx16;
typedef unsigned short ushort_t;

// ---------------------------------------------------------------------------
// ELL build: ell[out*S + k] = in  (slot unique per (out,k) -> no atomics)
// ---------------------------------------------------------------------------
__global__ void build_ell_kernel(const int* __restrict__ in_idx,
                                 const int* __restrict__ out_idx,
                                 int K, int S, int P, int n_in, int n_out,
                                 int* __restrict__ ell) {
  int i = blockIdx.x * 256 + threadIdx.x;
  if (i >= K * P) return;
  int vin = in_idx[i];
  int vout = out_idx[i];
  if (vin < n_in && vout < n_out) {
    ell[(size_t)vout * S + (i / P)] = vin;
  }
}

// ---------------------------------------------------------------------------
// Weight pack for 32x32x16 frags: W[k][ci][co] f32 -> Wp[k][ci/16][co][ci%16]
// ---------------------------------------------------------------------------
__global__ void pack_w_kernel(const float* __restrict__ W,
                              __hip_bfloat16* __restrict__ Wp,
                              int K, int CIN, int COUT) {
  long i = (long)blockIdx.x * 256 + threadIdx.x;
  long tot = (long)K * CIN * COUT;
  if (i >= tot) return;
  int co = (int)(i % COUT);
  long t = i / COUT;
  int ci = (int)(t % CIN);
  int k = (int)(t / CIN);
  float v = W[((long)k * CIN + ci) * COUT + co];
  Wp[(((long)k * (CIN / 16) + (ci >> 4)) * COUT + co) * 16 + (ci & 15)] =
      __float2bfloat16(v);
}

// conv0 weights: W0[125][1][64] -> Wp0[k/16][co][k%16], k padded to 128.
__global__ void pack_w0_kernel(const float* __restrict__ W,
                               __hip_bfloat16* __restrict__ Wp) {
  int i = blockIdx.x * 256 + threadIdx.x;
  if (i >= 128 * 64) return;
  int co = i & 63;
  int ki = i >> 6;
  float v = (ki < 125) ? W[ki * 64 + co] : 0.f;
  Wp[(((ki >> 4) * 64) + co) * 16 + (ki & 15)] = __float2bfloat16(v);
}

// feats f32 -> bf16 with one zero pad element at the end.
__global__ void f2bf_kernel(const float* __restrict__ x,
                            __hip_bfloat16* __restrict__ y, long n, long npad) {
  long i = (long)blockIdx.x * 256 + threadIdx.x;
  if (i >= npad) return;
  y[i] = __float2bfloat16(i < n ? x[i] : 0.f);
}

// Fixed-order sum of P partial buffers (deterministic).
__global__ void reduce_parts_kernel(const float* __restrict__ part, int P,
                                    long total, float* __restrict__ out) {
  long i = (long)blockIdx.x * 256 + threadIdx.x;
  if (i >= total) return;
  float s = 0.f;
  for (int p = 0; p < P; ++p) s += part[(size_t)p * total + i];
  out[i] = s;
}

// ---------------------------------------------------------------------------
// conv0: out[n0][64] = gatherA(x1ch, ell[*,128]) @ W0  via 32x32x16 MFMA.
// ---------------------------------------------------------------------------
__global__ __launch_bounds__(256, 2) void conv0_mfma_kernel(
    const ushort_t* __restrict__ xpad,   // [n0+1] bf16, [n0]=0
    const ushort_t* __restrict__ Wp0,    // [8][64][16]
    const int* __restrict__ ell,         // [n0][128]
    int n_out, float* __restrict__ out) {
  constexpr int STR = 152;               // 304 B row stride: 48 mod 128
  __shared__ ushort_t xs[64 * STR];
  const int tid = threadIdx.x;
  const int lane = tid & 63;
  const int wv = tid >> 6;
  const int wm = wv & 1, wn = wv >> 1;
  const long m0 = (long)blockIdx.x * 64;
  const int row = tid >> 2;
  const int kk0 = (tid & 3) * 32;
  const long grow = m0 + row;

  if (grow < n_out) {
    const ix4* ep = (const ix4*)(ell + grow * 128 + kk0);
#pragma unroll
    for (int g = 0; g < 8; ++g) {
      ix4 e = ep[g];
      sh4 v;
#pragma unroll
      for (int j = 0; j < 4; ++j) {
        int ix = (e[j] < 0) ? n_out : e[j];
        v[j] = (short)xpad[ix];
      }
      *(sh4*)(&xs[row * STR + kk0 + g * 4]) = v;
    }
  } else {
    sh4 z = (sh4)(short)0;
#pragma unroll
    for (int g = 0; g < 8; ++g) *(sh4*)(&xs[row * STR + kk0 + g * 4]) = z;
  }
  __syncthreads();

  const int arow = wm * 32 + (lane & 31);
  const int koff = (lane >> 5) * 8;
  const int bcol = wn * 32 + (lane & 31);
  floatx16 acc = (floatx16)(0.0f);
#pragma unroll
  for (int kc = 0; kc < 8; ++kc) {
    sh8 a = *(const sh8*)(&xs[arow * STR + kc * 16 + koff]);
    sh8 b = *(const sh8*)(Wp0 + ((size_t)kc * 64 + bcol) * 16 + koff);
    acc = __builtin_amdgcn_mfma_f32_32x32x16_bf16(a, b, acc, 0, 0, 0);
  }
  const int lrow = (lane >> 5) * 4;
#pragma unroll
  for (int r = 0; r < 16; ++r) {
    long orow = m0 + wm * 32 + (r & 3) + 8 * (r >> 2) + lrow;
    if (orow < n_out) out[orow * 64 + bcol] = acc[r];
  }
}

// ---------------------------------------------------------------------------
// Main MFMA implicit-GEMM sparse conv. Block 256 = 4 waves (2M x 2N), BM=64.
// blockIdx.y = offset partition (split-K): handles k in [y*KP, min(K,(y+1)*KP))
// writing to out + y*n_out*COUT (reduced afterwards when gridDim.y > 1).
// ell==nullptr -> dense 1x1 (in = row). xb has a zero pad row at n_in.
// ---------------------------------------------------------------------------
template <int CIN, int COUT>
__global__ __launch_bounds__(256, 2) void conv_mfma_kernel(
    const ushort_t* __restrict__ xb, const ushort_t* __restrict__ Wp,
    const int* __restrict__ ell, int K, int KP, int n_out, int n_in,
    float* __restrict__ out) {
  constexpr int KC = CIN / 16;    // k-chunks of 16
  constexpr int NT = COUT / 64;   // 32-col frags per wave
  constexpr int STR = CIN + 24;   // row stride: 48 mod 128 bytes -> 4-way max
  constexpr int CH = CIN / 32;    // sh8 chunks per thread for staging
  __shared__ ushort_t xs[2][64 * STR];
  const int tid = threadIdx.x;
  const int lane = tid & 63;
  const int wv = tid >> 6;
  const int wm = wv & 1, wn = wv >> 1;
  const long m0 = (long)blockIdx.x * 64;
  const int srow = tid >> 2;
  const int scol = (tid & 3) * (CIN / 4);
  const long grow = m0 + srow;

  const int k0 = blockIdx.y * KP;
  int k1 = k0 + KP;
  if (k1 > K) k1 = K;
  out += (size_t)blockIdx.y * ((size_t)n_out * COUT);

  floatx16 acc[NT];
#pragma unroll
  for (int t = 0; t < NT; ++t) acc[t] = (floatx16)(0.0f);

  sh8 sreg[CH];
  auto issue = [&](int k) {
    int in = n_in;  // pad row (zeros)
    if (grow < n_out) {
      int e = ell ? ell[grow * K + k] : (int)grow;
      if (e >= 0) in = e;
    }
    const ushort_t* src = xb + (size_t)in * CIN + scol;
#pragma unroll
    for (int c = 0; c < CH; ++c) sreg[c] = *(const sh8*)(src + c * 8);
  };
  auto commit = [&](int buf) {
    ushort_t* dst = &xs[buf][srow * STR + scol];
#pragma unroll
    for (int c = 0; c < CH; ++c) *(sh8*)(dst + c * 8) = sreg[c];
  };

  if (k0 < k1) {
    issue(k0);
    commit(0);
  }
  __syncthreads();

  const int arow = wm * 32 + (lane & 31);
  const int koff = (lane >> 5) * 8;
  const int bcol = wn * (COUT / 2) + (lane & 31);
  for (int k = k0; k < k1; ++k) {
    const int cur = (k - k0) & 1;
    if (k + 1 < k1) issue(k + 1);  // global loads in flight under compute
    sh8 a[KC];
#pragma unroll
    for (int kc = 0; kc < KC; ++kc)
      a[kc] = *(const sh8*)(&xs[cur][arow * STR + kc * 16 + koff]);
    const ushort_t* wk = Wp + ((size_t)k * KC * COUT + bcol) * 16 + koff;
#pragma unroll
    for (int t = 0; t < NT; ++t) {
#pragma unroll
      for (int kc = 0; kc < KC; ++kc) {
        sh8 b = *(const sh8*)(wk + ((size_t)kc * COUT + t * 32) * 16);
        acc[t] =
            __builtin_amdgcn_mfma_f32_32x32x16_bf16(a[kc], b, acc[t], 0, 0, 0);
      }
    }
    if (k + 1 < k1) {
      __syncthreads();       // all waves done reading xs[cur^1]
      commit(cur ^ 1);
      __syncthreads();       // writes visible before next step reads
    }
  }

  const int ccol = wn * (COUT / 2) + (lane & 31);
  const int lrowb = wm * 32 + (lane >> 5) * 4;
#pragma unroll
  for (int t = 0; t < NT; ++t) {
#pragma unroll
    for (int r = 0; r < 16; ++r) {
      long row = m0 + lrowb + (r & 3) + 8 * (r >> 2);
      if (row < n_out) out[row * COUT + ccol + t * 32] = acc[t][r];
    }
  }
}

// ---------------------------------------------------------------------------
// BN: deterministic two-pass stats + fused apply (residual/ReLU/bf16 + pad).
// ---------------------------------------------------------------------------
template <int C>
__global__ void bn_reduce1_kernel(const float* __restrict__ x, int n,
                                  float* __restrict__ part) {
  constexpr int RL = 256 / C;
  const int c = threadIdx.x % C;
  const int rl = threadIdx.x / C;
  float s = 0.f, ss = 0.f;
  for (long row = (long)blockIdx.x * RL + rl; row < n;
       row += (long)gridDim.x * RL) {
    float v = x[row * C + c];
    s += v;
    ss += v * v;
  }
  __shared__ float sh[512];
  sh[threadIdx.x] = s;
  sh[256 + threadIdx.x] = ss;
  __syncthreads();
  if (rl == 0) {
#pragma unroll
    for (int j = 1; j < RL; ++j) {
      s += sh[j * C + c];
      ss += sh[256 + j * C + c];
    }
    part[(size_t)blockIdx.x * 2 * C + c] = s;
    part[(size_t)blockIdx.x * 2 * C + C + c] = ss;
  }
}

template <int C>
__global__ void bn_reduce2_kernel(const float* __restrict__ part, int G,
                                  float* __restrict__ stats) {
  const int c = threadIdx.x;
  float s = 0.f, ss = 0.f;
  for (int g = 0; g < G; ++g) {
    s += part[(size_t)g * 2 * C + c];
    ss += part[(size_t)g * 2 * C + C + c];
  }
  stats[c] = s;
  stats[C + c] = ss;
}

template <int C, bool RELU, bool RES>
__global__ void bn_apply_kernel(const float* __restrict__ x,
                                const float* __restrict__ stats,
                                const float* __restrict__ gamma,
                                const float* __restrict__ beta,
                                const float* __restrict__ res,
                                long total, float inv_n,
                                float* __restrict__ out,
                                __hip_bfloat16* __restrict__ outb) {
  long i = (long)blockIdx.x * 256 + threadIdx.x;
  if (i >= total) {
    if (outb && i < total + C) outb[i] = __float2bfloat16(0.f);  // pad row
    return;
  }
  const int c = (int)(i % C);
  const float m = stats[c] * inv_n;
  const float var = stats[C + c] * inv_n - m * m;
  const float sc = rsqrtf(var + 1e-5f) * gamma[c];
  float v = (x[i] - m) * sc + beta[c];
  if (RES) v += res[i];
  if (RELU) v = fmaxf(v, 0.f);
  out[i] = v;
  if (outb) outb[i] = __float2bfloat16(v);
}

// ---------------------------------------------------------------------------

extern "C" void kernel_launch(void* const* d_in, const int* in_sizes, int n_in,
                              void* d_out, int out_size, void* d_ws,
                              size_t ws_size, hipStream_t stream) {
  const float* feats = (const float*)d_in[0];
  const float* W0  = (const float*)d_in[1];
  const float* g0  = (const float*)d_in[2];
  const float* b0  = (const float*)d_in[3];
  const float* Ws1 = (const float*)d_in[4];
  const float* gs1 = (const float*)d_in[5];
  const float* bs1 = (const float*)d_in[6];
  const float* Wa1 = (const float*)d_in[7];
  const float* ga1 = (const float*)d_in[8];
  const float* ba1 = (const float*)d_in[9];
  const float* Wb1 = (const float*)d_in[10];
  const float* gb1 = (const float*)d_in[11];
  const float* bb1 = (const float*)d_in[12];
  const float* Ws2 = (const float*)d_in[13];
  const float* gs2 = (const float*)d_in[14];
  const float* bs2 = (const float*)d_in[15];
  const float* Wa2 = (const float*)d_in[16];
  const float* ga2 = (const float*)d_in[17];
  const float* ba2 = (const float*)d_in[18];
  const float* Wb2 = (const float*)d_in[19];
  const float* gb2 = (const float*)d_in[20];
  const float* bb2 = (const float*)d_in[21];
  const float* Wd2 = (const float*)d_in[22];
  const float* gd2 = (const float*)d_in[23];
  const float* bd2 = (const float*)d_in[24];
  const float* Ws3 = (const float*)d_in[25];
  const float* gs3 = (const float*)d_in[26];
  const float* bs3 = (const float*)d_in[27];
  const float* Wa3 = (const float*)d_in[28];
  const float* ga3 = (const float*)d_in[29];
  const float* ba3 = (const float*)d_in[30];
  const float* Wb3 = (const float*)d_in[31];
  const float* gb3 = (const float*)d_in[32];
  const float* bb3 = (const float*)d_in[33];
  const float* Wd3 = (const float*)d_in[34];
  const float* gd3 = (const float*)d_in[35];
  const float* bd3 = (const float*)d_in[36];
  const int* im0  = (const int*)d_in[40];
  const int* om0  = (const int*)d_in[41];
  const int* ims1 = (const int*)d_in[42];
  const int* oms1 = (const int*)d_in[43];
  const int* imb1 = (const int*)d_in[44];
  const int* omb1 = (const int*)d_in[45];
  const int* ims2 = (const int*)d_in[46];
  const int* oms2 = (const int*)d_in[47];
  const int* imb2 = (const int*)d_in[48];
  const int* omb2 = (const int*)d_in[49];
  const int* ims3 = (const int*)d_in[50];
  const int* oms3 = (const int*)d_in[51];
  const int* imb3 = (const int*)d_in[52];
  const int* omb3 = (const int*)d_in[53];

  const int n0 = in_sizes[0];
  const int n1 = in_sizes[37] / 3;
  const int n2 = in_sizes[38] / 3;
  const int n3 = in_sizes[39] / 3;
  const int P0  = in_sizes[40] / 125;
  const int Ps1 = in_sizes[42] / 8;
  const int Pb1 = in_sizes[44] / 27;
  const int Ps2 = in_sizes[46] / 8;
  const int Pb2 = in_sizes[48] / 27;
  const int Ps3 = in_sizes[50] / 8;
  const int Pb3 = in_sizes[52] / 27;

  // ---- workspace carve ----
  char* w = (char*)d_ws;
  auto carve = [&](size_t bytes) {
    char* p = w;
    w += (bytes + 255) & ~(size_t)255;
    return p;
  };
  int* ellS = (int*)carve((size_t)n0 * 128 * sizeof(int));
  int* ellB = (int*)carve((size_t)n1 * 27 * sizeof(int));
  float* part = (float*)carve((size_t)256 * 512 * sizeof(float));
  float* stats = (float*)carve((size_t)512 * sizeof(float));
  size_t capE = (size_t)n0 * 64 + 256;  // + pad row
  float* buf1 = (float*)carve(capE * sizeof(float));
  float* buf2 = (float*)carve(capE * sizeof(float));
  float* buf3 = (float*)carve(capE * sizeof(float));
  __hip_bfloat16* bbA = (__hip_bfloat16*)carve(capE * 2);
  __hip_bfloat16* bbB = (__hip_bfloat16*)carve(capE * 2);
  __hip_bfloat16* bbC = (__hip_bfloat16*)carve(capE * 2);
  __hip_bfloat16* xfeat = (__hip_bfloat16*)carve(((size_t)n0 + 1) * 2);

  // ---- weight packing ----
  auto pack = [&](const float* W, int K, int cin, int cout) {
    __hip_bfloat16* Wp = (__hip_bfloat16*)carve((size_t)K * cin * cout * 2);
    long tot = (long)K * cin * cout;
    pack_w_kernel<<<(int)((tot + 255) / 256), 256, 0, stream>>>(W, Wp, K, cin,
                                                                cout);
    return Wp;
  };
  __hip_bfloat16* Wp0 = (__hip_bfloat16*)carve((size_t)128 * 64 * 2);
  pack_w0_kernel<<<32, 256, 0, stream>>>(W0, Wp0);
  __hip_bfloat16* Ps1p = pack(Ws1, 8, 64, 64);
  __hip_bfloat16* Pa1p = pack(Wa1, 27, 64, 64);
  __hip_bfloat16* Pb1p = pack(Wb1, 27, 64, 64);
  __hip_bfloat16* Ps2p = pack(Ws2, 8, 64, 64);
  __hip_bfloat16* Pd2p = pack(Wd2, 1, 64, 128);
  __hip_bfloat16* Pa2p = pack(Wa2, 27, 64, 128);
  __hip_bfloat16* Pb2p = pack(Wb2, 27, 128, 128);
  __hip_bfloat16* Ps3p = pack(Ws3, 8, 128, 128);
  __hip_bfloat16* Pd3p = pack(Wd3, 1, 128, 256);
  __hip_bfloat16* Pa3p = pack(Wa3, 27, 128, 256);
  __hip_bfloat16* Pb3p = pack(Wb3, 27, 256, 256);

  // split-K partial buffer: all remaining workspace
  size_t used = (size_t)(w - (char*)d_ws);
  float* pbuf = (float*)w;
  size_t pcap = (ws_size > used) ? (ws_size - used) / sizeof(float) : 0;

  f2bf_kernel<<<(int)((n0 + 256) / 256), 256, 0, stream>>>(feats, xfeat, n0,
                                                           n0 + 1);

  auto buildEll = [&](int* ellbuf, const int* im, const int* om, int K, int S,
                      int P, int nin, int nout) {
    hipMemsetAsync(ellbuf, 0xFF, (size_t)nout * S * sizeof(int), stream);
    int tot = K * P;
    build_ell_kernel<<<(tot + 255) / 256, 256, 0, stream>>>(im, om, K, S, P,
                                                            nin, nout, ellbuf);
  };

  auto convm = [&](const __hip_bfloat16* xb, const __hip_bfloat16* Wp,
                   const int* ellp, int K, int nout, int nin, int cin,
                   int cout, float* outp) {
    int mblocks = (nout + 63) / 64;
    int ks = 1;
    if (ellp && mblocks < 256) {
      int desired = (512 + mblocks - 1) / mblocks;
      if (desired > 8) desired = 8;
      if (desired > K) desired = K;
      size_t need = (size_t)nout * cout;
      int fit = (need > 0) ? (int)(pcap / need) : 1;
      ks = desired < fit ? desired : fit;
      if (ks < 1) ks = 1;
    }
    int KP = (K + ks - 1) / ks;
    float* tgt = (ks > 1) ? pbuf : outp;
    dim3 grid(mblocks, ks);
#define CM_CASE(CI, CO)                                                        \
  else if (cin == CI && cout == CO) {                                          \
    conv_mfma_kernel<CI, CO><<<grid, 256, 0, stream>>>(                        \
        (const ushort_t*)xb, (const ushort_t*)Wp, ellp, K, KP, nout, nin,      \
        tgt);                                                                  \
  }
    if (false) {}
    CM_CASE(64, 64)
    CM_CASE(64, 128)
    CM_CASE(128, 128)
    CM_CASE(128, 256)
    CM_CASE(256, 256)
#undef CM_CASE
    if (ks > 1) {
      long total = (long)nout * cout;
      reduce_parts_kernel<<<(int)((total + 255) / 256), 256, 0, stream>>>(
          pbuf, ks, total, outp);
    }
  };

  auto bn = [&](const float* x, int n, int C, const float* gamma,
                const float* beta, const float* res, bool relu, float* outp,
                __hip_bfloat16* outb) {
    const int G = 256;
    float invn = 1.0f / (float)n;
    long total = (long)n * C;
    int agrid = (int)((total + C + 255) / 256);
#define BN_CASE(CC)                                                            \
  else if (C == CC) {                                                          \
    bn_reduce1_kernel<CC><<<G, 256, 0, stream>>>(x, n, part);                  \
    bn_reduce2_kernel<CC><<<1, CC, 0, stream>>>(part, G, stats);               \
    if (res && relu)                                                           \
      bn_apply_kernel<CC, true, true><<<agrid, 256, 0, stream>>>(              \
          x, stats, gamma, beta, res, total, invn, outp, outb);                \
    else if (relu)                                                             \
      bn_apply_kernel<CC, true, false><<<agrid, 256, 0, stream>>>(             \
          x, stats, gamma, beta, nullptr, total, invn, outp, outb);            \
    else                                                                       \
      bn_apply_kernel<CC, false, false><<<agrid, 256, 0, stream>>>(            \
          x, stats, gamma, beta, nullptr, total, invn, outp, outb);            \
  }
    if (false) {}
    BN_CASE(64)
    BN_CASE(128)
    BN_CASE(256)
#undef BN_CASE
  };

  float* y1 = (float*)d_out;
  float* y2 = y1 + (size_t)n1 * 64;
  float* y3 = y2 + (size_t)n2 * 128;

  // ---- stem: conv0 (k=125 -> GEMM over K=128) + BN ----
  buildEll(ellS, im0, om0, 125, 128, P0, n0, n0);
  conv0_mfma_kernel<<<(n0 + 63) / 64, 256, 0, stream>>>(
      (const ushort_t*)xfeat, (const ushort_t*)Wp0, ellS, n0, buf1);
  bn(buf1, n0, 64, g0, b0, nullptr, true, buf1, bbA);               // x0

  // ---- level 1 ----
  buildEll(ellS, ims1, oms1, 8, 8, Ps1, n0, n1);
  convm(bbA, Ps1p, ellS, 8, n1, n0, 64, 64, buf2);
  bn(buf2, n1, 64, gs1, bs1, nullptr, true, buf2, bbB);             // x1
  buildEll(ellB, imb1, omb1, 27, 27, Pb1, n1, n1);
  convm(bbB, Pa1p, ellB, 27, n1, n1, 64, 64, buf3);
  bn(buf3, n1, 64, ga1, ba1, nullptr, true, buf3, bbC);             // h1a
  convm(bbC, Pb1p, ellB, 27, n1, n1, 64, 64, buf1);
  bn(buf1, n1, 64, gb1, bb1, buf2, true, y1, bbA);                  // y1

  // ---- level 2 ----
  buildEll(ellS, ims2, oms2, 8, 8, Ps2, n1, n2);
  convm(bbA, Ps2p, ellS, 8, n2, n1, 64, 64, buf3);
  bn(buf3, n2, 64, gs2, bs2, nullptr, true, buf3, bbB);             // x2
  convm(bbB, Pd2p, nullptr, 1, n2, n2, 64, 128, buf1);
  bn(buf1, n2, 128, gd2, bd2, nullptr, false, buf1, nullptr);       // res2
  buildEll(ellB, imb2, omb2, 27, 27, Pb2, n2, n2);
  convm(bbB, Pa2p, ellB, 27, n2, n2, 64, 128, buf2);
  bn(buf2, n2, 128, ga2, ba2, nullptr, true, buf2, bbC);            // h2a
  convm(bbC, Pb2p, ellB, 27, n2, n2, 128, 128, buf3);
  bn(buf3, n2, 128, gb2, bb2, buf1, true, y2, bbA);                 // y2

  // ---- level 3 ----
  buildEll(ellS, ims3, oms3, 8, 8, Ps3, n2, n3);
  convm(bbA, Ps3p, ellS, 8, n3, n2, 128, 128, buf2);
  bn(buf2, n3, 128, gs3, bs3, nullptr, true, buf2, bbB);            // x3
  convm(bbB, Pd3p, nullptr, 1, n3, n3, 128, 256, buf1);
  bn(buf1, n3, 256, gd3, bd3, nullptr, false, buf1, nullptr);       // res3
  buildEll(ellB, imb3, omb3, 27, 27, Pb3, n3, n3);
  convm(bbB, Pa3p, ellB, 27, n3, n3, 128, 256, buf3);
  bn(buf3, n3, 256, ga3, ba3, nullptr, true, buf3, bbC);            // h3a
  convm(bbC, Pb3p, ellB, 27, n3, n3, 256, 256, buf2);
  bn(buf2, n3, 256, gb3, bb3, buf1, true, y3, nullptr);             // y3
}